// Round 6
// baseline (774.960 us; speedup 1.0000x reference)
//
#include <hip/hip_runtime.h>
#include <stdint.h>

#define NTOK 16384
#define HD   1024
#define SD   256
#define NE   8

typedef short bf16x8 __attribute__((ext_vector_type(8)));
typedef _Float16 f16x8 __attribute__((ext_vector_type(8)));
typedef float f32x4 __attribute__((ext_vector_type(4)));
typedef unsigned short u16;
typedef unsigned short u16x8 __attribute__((ext_vector_type(8)));

__device__ __forceinline__ u16 f2bf(float f) {
  union { float f; unsigned u; } v; v.f = f;
  return (u16)((v.u + 0x7fffu + ((v.u >> 16) & 1u)) >> 16);
}

__device__ __forceinline__ void gload16(const void* g, void* l) {
  __builtin_amdgcn_global_load_lds((const __attribute__((address_space(1))) void*)g,
                                   (__attribute__((address_space(3))) void*)l,
                                   16, 0, 0);
}

// meta layout (ints): [0..7] counts, [8..15] cursors, [16..24] offsets,
// [25] ntiles(256-row), [32..191] tile_e, [192..351] tile_row0, [352..511] tile_end

// LDS chunk-XOR swizzle (all 3 GEMMs): tile rows are 32 u16 = 4 chunks of 16B.
// LDS[row][slot] holds global chunk (slot ^ ((row>>1)&3)). Staging lane l reads
// global chunk (l&3)^((l>>3)&3) of row l>>2 -> each 4-lane group still covers
// one contiguous 64B row segment (VMEM coalescing identical) and the linear
// gload_lds dest produces the swizzled layout. Fragment read lane l uses slot
// (l>>4)^((l>>1)&3): conflict-free ds_read_b128 (verified: conflicts 8.7M -> 0).

// ---------------- Fused prep: aprep (8192 blk) + bprep (64 blk) + tconv (4608 blk) ----------------
__global__ __launch_bounds__(256) void prep_kernel(
    const float* __restrict__ ue, _Float16* __restrict__ aP,
    const float* __restrict__ sw1, _Float16* __restrict__ bP,
    const float* __restrict__ ew1, const float* __restrict__ ew2,
    const float* __restrict__ uw1, const float* __restrict__ uw2,
    u16* __restrict__ ew1t, u16* __restrict__ ew2t,
    u16* __restrict__ uw1t, u16* __restrict__ uw2t) {
  const int bid = blockIdx.x;
  const int tid = threadIdx.x;
  if (bid < 8192) {
    // --- aprep: ue f32 -> A' = [hi | lo] fp16, row stride 2048 ---
    const int t = bid * 256 + tid;
    const int p = t >> 7;
    const int h = (t & 127) << 3;
    const float* s = ue + ((size_t)p << 10) + h;
    const float4 a = *(const float4*)s;
    const float4 b = *(const float4*)(s + 4);
    float v[8] = {a.x, a.y, a.z, a.w, b.x, b.y, b.z, b.w};
    f16x8 hi, lo;
#pragma unroll
    for (int j = 0; j < 8; ++j) {
      const _Float16 h16 = (_Float16)v[j];
      hi[j] = h16;
      lo[j] = (_Float16)(v[j] - (float)h16);
    }
    _Float16* d = aP + ((size_t)p << 11) + h;
    *(f16x8*)d = hi;
    *(f16x8*)(d + 1024) = lo;
    return;
  }
  __shared__ float tb[64][65];
  if (bid < 8256) {
    // --- bprep: sw1 [1024][256] f32 -> B' [256][3072] fp16 = [hi|lo|hi] ---
    const int b = bid - 8192;
    const int c0 = (b & 3) << 6;
    const int r0 = (b >> 2) << 6;
    {
      const int lr = tid >> 2, q = (tid & 3) << 4;
      const float* s = sw1 + (size_t)(r0 + lr) * SD + c0 + q;
#pragma unroll
      for (int j = 0; j < 16; j += 4) {
        const float4 v = *(const float4*)(s + j);
        tb[lr][q + j] = v.x; tb[lr][q + j + 1] = v.y;
        tb[lr][q + j + 2] = v.z; tb[lr][q + j + 3] = v.w;
      }
    }
    __syncthreads();
    const int lc = tid >> 2, rq = (tid & 3) << 4;
    f16x8 hi0, hi1, lo0, lo1;
#pragma unroll
    for (int j = 0; j < 8; ++j) {
      const float v0 = tb[rq + j][lc];
      const _Float16 h0 = (_Float16)v0;
      hi0[j] = h0; lo0[j] = (_Float16)(v0 - (float)h0);
      const float v1 = tb[rq + 8 + j][lc];
      const _Float16 h1 = (_Float16)v1;
      hi1[j] = h1; lo1[j] = (_Float16)(v1 - (float)h1);
    }
    _Float16* d = bP + (size_t)(c0 + lc) * 3072 + r0 + rq;
    *(f16x8*)d = hi0;           *(f16x8*)(d + 8) = hi1;
    *(f16x8*)(d + 1024) = lo0;  *(f16x8*)(d + 1032) = lo1;
    *(f16x8*)(d + 2048) = hi0;  *(f16x8*)(d + 2056) = hi1;
    return;
  }
  // --- tconv: transpose+convert 1024x1024 f32 -> bf16, 18 matrices ---
  const int c = bid - 8256;
  const int m = c >> 8;
  const int t2 = c & 255;
  const int c0 = (t2 & 15) << 6;
  const int r0 = (t2 >> 4) << 6;
  const size_t msz = (size_t)HD * HD;
  const float* src; u16* dst;
  if (m < 8)       { src = ew1 + (size_t)m * msz;       dst = ew1t + (size_t)m * msz; }
  else if (m < 16) { src = ew2 + (size_t)(m - 8) * msz; dst = ew2t + (size_t)(m - 8) * msz; }
  else if (m == 16){ src = uw1;                          dst = uw1t; }
  else             { src = uw2;                          dst = uw2t; }
  {
    const int lr = tid >> 2, q = (tid & 3) << 4;
    const float* s = src + (size_t)(r0 + lr) * HD + c0 + q;
#pragma unroll
    for (int j = 0; j < 16; j += 4) {
      const float4 v = *(const float4*)(s + j);
      tb[lr][q + j] = v.x; tb[lr][q + j + 1] = v.y;
      tb[lr][q + j + 2] = v.z; tb[lr][q + j + 3] = v.w;
    }
  }
  __syncthreads();
  {
    const int lc = tid >> 2, rq = (tid & 3) << 4;
    u16x8 o0, o1;
#pragma unroll
    for (int j = 0; j < 8; ++j) o0[j] = f2bf(tb[rq + j][lc]);
#pragma unroll
    for (int j = 0; j < 8; ++j) o1[j] = f2bf(tb[rq + 8 + j][lc]);
    u16* d = dst + (size_t)(c0 + lc) * HD + r0 + rq;
    *(u16x8*)d = o0;
    *(u16x8*)(d + 8) = o1;
  }
}

// ---------------- Router GEMM: hidden[p][s] = relu(3-term hi/lo fp16 MFMA + sb1), f32 out ----------------
__global__ __launch_bounds__(256) void rgemm_kernel(
    const _Float16* __restrict__ aP, const _Float16* __restrict__ bP,
    const float* __restrict__ sb1, float* __restrict__ hidden) {
  const int p = blockIdx.x;
  const int L = (p & 7) * 64 + (p >> 3);
  const int jt = L & 3;           // 64-col tile
  const int row0 = (L >> 2) << 7; // 128-row tile

  __shared__ _Float16 sA[2][128 * 32];
  __shared__ _Float16 sB[2][64 * 32];

  const int tid = threadIdx.x, lane = tid & 63, wave = tid >> 6;
  const int wr = (wave >> 1) << 6, wc = (wave & 1) << 5;
  const int smrow = tid >> 2, skoff = (((tid & 3) ^ ((tid >> 3) & 3)) << 3);
  const _Float16* ar0 = aP + ((size_t)(row0 + smrow) << 11) + skoff;
  const _Float16* ar1 = aP + ((size_t)(row0 + smrow + 64) << 11) + skoff;
  const _Float16* br  = bP + (size_t)((jt << 6) + smrow) * 3072 + skoff;
  const int ldsoff = wave << 10;

  f32x4 acc[4][2];
#pragma unroll
  for (int i = 0; i < 4; ++i)
#pragma unroll
    for (int j = 0; j < 2; ++j) acc[i][j] = (f32x4){0.f, 0.f, 0.f, 0.f};

  gload16(ar0, (char*)sA[0] + ldsoff);
  gload16(ar1, (char*)sA[0] + 4096 + ldsoff);
  gload16(br,  (char*)sB[0] + ldsoff);

  const int sl = (((lane >> 4) ^ ((lane >> 1) & 3)) << 3);
  const int afrag = (wr + (lane & 15)) * 32 + sl;
  const int bfrag = (wc + (lane & 15)) * 32 + sl;

  for (int ks = 0; ks < 96; ++ks) {
    const int buf = ks & 1;
    __syncthreads();
    if (ks + 1 < 96) {
      const int k1 = ks + 1;
      const int pa = (k1 < 64) ? ((k1 & 31) << 5) : (1024 + ((k1 - 64) << 5));
      gload16(ar0 + pa, (char*)sA[buf ^ 1] + ldsoff);
      gload16(ar1 + pa, (char*)sA[buf ^ 1] + 4096 + ldsoff);
      gload16(br + (k1 << 5), (char*)sB[buf ^ 1] + ldsoff);
    }
    f16x8 av[4], bv[2];
#pragma unroll
    for (int f = 0; f < 4; ++f) av[f] = *(const f16x8*)&sA[buf][afrag + f * 512];
#pragma unroll
    for (int f = 0; f < 2; ++f) bv[f] = *(const f16x8*)&sB[buf][bfrag + f * 512];
#pragma unroll
    for (int i = 0; i < 4; ++i)
#pragma unroll
      for (int j = 0; j < 2; ++j)
        acc[i][j] = __builtin_amdgcn_mfma_f32_16x16x32_f16(av[i], bv[j], acc[i][j], 0, 0, 0);
  }

  const int lc = lane & 15, lr4 = (lane >> 4) << 2;
#pragma unroll
  for (int j = 0; j < 2; ++j) {
    const int c = (jt << 6) + wc + (j << 4) + lc;
    const float bias = sb1[c];
#pragma unroll
    for (int i = 0; i < 4; ++i) {
      const int rl = wr + (i << 4) + lr4;
#pragma unroll
      for (int q = 0; q < 4; ++q)
        hidden[((size_t)(row0 + rl + q) << 8) + c] = fmaxf(acc[i][j][q] + bias, 0.f);
    }
  }
}

// ---------------- Logits layer-2 (f32, fixed order) + argmax + histogram ----------------
__global__ __launch_bounds__(256) void logits_kernel(
    const float* __restrict__ hidden, const float* __restrict__ sw2,
    const float* __restrict__ sb2, int* __restrict__ routes, int* meta) {
  __shared__ float logl[32][8];
  const int tid = threadIdx.x;
  const int tok0 = blockIdx.x << 5;
  const int tl = tid >> 3, e2 = tid & 7;
  const float* hp = hidden + ((size_t)(tok0 + tl) << 8);
  float a0 = 0.f, a1 = 0.f, a2 = 0.f, a3 = 0.f;
  for (int q = 0; q < SD; q += 8) {
    const float4 h0 = *(const float4*)&hp[q];
    const float4 h1 = *(const float4*)&hp[q + 4];
    a0 = fmaf(h0.x, sw2[((q + 0) << 3) + e2], a0);
    a1 = fmaf(h0.y, sw2[((q + 1) << 3) + e2], a1);
    a2 = fmaf(h0.z, sw2[((q + 2) << 3) + e2], a2);
    a3 = fmaf(h0.w, sw2[((q + 3) << 3) + e2], a3);
    a0 = fmaf(h1.x, sw2[((q + 4) << 3) + e2], a0);
    a1 = fmaf(h1.y, sw2[((q + 5) << 3) + e2], a1);
    a2 = fmaf(h1.z, sw2[((q + 6) << 3) + e2], a2);
    a3 = fmaf(h1.w, sw2[((q + 7) << 3) + e2], a3);
  }
  logl[tl][e2] = (a0 + a1) + (a2 + a3) + sb2[e2];
  __syncthreads();
  if (tid < 32) {
    float best = logl[tid][0]; int be = 0;
#pragma unroll
    for (int e = 1; e < 8; ++e) {
      const float v = logl[tid][e];
      if (v > best) { best = v; be = e; }
    }
    routes[tok0 + tid] = be;
    atomicAdd(&meta[be], 1);
  }
}

// ---------------- Scan: offsets + 256-row tile table ----------------
__global__ void scan_kernel(int* meta) {
  if (threadIdx.x != 0) return;
  int off = 0;
  for (int e = 0; e < NE; ++e) { meta[16 + e] = off; off += meta[e]; }
  meta[24] = off;
  int nt = 0;
  for (int e = 0; e < NE; ++e) {
    const int s = meta[16 + e], en = meta[16 + e + 1];
    for (int r0 = s; r0 < en; r0 += 256) {
      meta[32 + nt] = e; meta[192 + nt] = r0; meta[352 + nt] = en; ++nt;
    }
  }
  meta[25] = nt;
}

// ---------------- Build permutation (token -> grouped position) ----------------
__global__ void perm_kernel(const int* __restrict__ routes, int* meta, int* __restrict__ perm) {
  const int b = blockIdx.x * 256 + threadIdx.x;
  const int r = routes[b];
  const int pos = meta[16 + r] + atomicAdd(&meta[8 + r], 1);
  perm[pos] = b;
}

// ---------------- Gather x rows into grouped order, f32 -> bf16 ----------------
__global__ __launch_bounds__(256) void gatherx_kernel(
    const float* __restrict__ x, const int* __restrict__ perm, u16* __restrict__ xg) {
  const int t = blockIdx.x * 256 + threadIdx.x;
  const int p = t >> 7;
  const int j = (t & 127) << 3;
  const int tok = perm[p];
  const float* s = &x[((size_t)tok << 10) + j];
  const float4 a = *(const float4*)s;
  const float4 b = *(const float4*)(s + 4);
  u16x8 o;
  o[0] = f2bf(a.x); o[1] = f2bf(a.y); o[2] = f2bf(a.z); o[3] = f2bf(a.w);
  o[4] = f2bf(b.x); o[5] = f2bf(b.y); o[6] = f2bf(b.z); o[7] = f2bf(b.w);
  *(u16x8*)&xg[((size_t)p << 10) + j] = o;
}

// ---------------- GEMM1: 256x128 tile, per-wave 128x64 (acc 8x4), BK=32 ----------------
// Same double-buffer schedule + swizzle as round-5; M-tile doubled so per-K-step
// overhead (barrier, drain, addr VALU) is amortized over 32 MFMA/wave not 16.
// LDS 48 KB -> 3 blocks/CU.
__global__ __launch_bounds__(256) void gemm1_kernel(
    const u16* __restrict__ xg, const u16* __restrict__ ew1t,
    const u16* __restrict__ uw1t, const float* __restrict__ eb1,
    const float* __restrict__ ub1, const int* __restrict__ meta,
    u16* __restrict__ hid) {
  const int nt = meta[25];
  // grid 1152 = 8 * 144 (XCD-bijective), mt-major: 72 mt x 16 jt
  const int pb = blockIdx.x;
  const int L = (pb & 7) * 144 + (pb >> 3);
  const int mt = L >> 4;
  const int jt = L & 15;
  if (mt >= nt) return;
  const int e = meta[32 + mt], row0 = meta[192 + mt], gend = meta[352 + mt];
  const u16* wbase = (jt < 8)
      ? ew1t + ((size_t)e << 20) + ((size_t)(jt << 7) << 10)
      : uw1t + ((size_t)((jt - 8) << 7) << 10);

  __shared__ u16 sA[2][256 * 32];
  __shared__ u16 sB[2][128 * 32];

  const int tid = threadIdx.x;
  const int lane = tid & 63;
  const int wave = tid >> 6;
  const int wr = (wave >> 1) << 7;   // 0 / 128
  const int wc = (wave & 1) << 6;    // 0 / 64

  const int smrow = tid >> 2;
  const int skoff = (((tid & 3) ^ ((tid >> 3) & 3)) << 3);
  // A staging rows clamped (tail tiles may exceed token count; masked at store)
  int r0c = row0 + smrow;       if (r0c > NTOK - 1) r0c = NTOK - 1;
  int r1c = row0 + smrow + 64;  if (r1c > NTOK - 1) r1c = NTOK - 1;
  int r2c = row0 + smrow + 128; if (r2c > NTOK - 1) r2c = NTOK - 1;
  int r3c = row0 + smrow + 192; if (r3c > NTOK - 1) r3c = NTOK - 1;
  const u16* ap0 = xg + (((size_t)r0c) << 10) + skoff;
  const u16* ap1 = xg + (((size_t)r1c) << 10) + skoff;
  const u16* ap2 = xg + (((size_t)r2c) << 10) + skoff;
  const u16* ap3 = xg + (((size_t)r3c) << 10) + skoff;
  const u16* bp0 = wbase + (((size_t)smrow) << 10) + skoff;
  const u16* bp1 = wbase + (((size_t)(smrow + 64)) << 10) + skoff;
  const int ldsoff = wave << 10;

  f32x4 acc[8][4];
#pragma unroll
  for (int i = 0; i < 8; ++i)
#pragma unroll
    for (int j = 0; j < 4; ++j) acc[i][j] = (f32x4){0.f, 0.f, 0.f, 0.f};

  gload16(ap0, (char*)sA[0] + ldsoff);
  gload16(ap1, (char*)sA[0] + 4096 + ldsoff);
  gload16(ap2, (char*)sA[0] + 8192 + ldsoff);
  gload16(ap3, (char*)sA[0] + 12288 + ldsoff);
  gload16(bp0, (char*)sB[0] + ldsoff);
  gload16(bp1, (char*)sB[0] + 4096 + ldsoff);

  const int sl = (((lane >> 4) ^ ((lane >> 1) & 3)) << 3);
  const int afrag = (wr + (lane & 15)) * 32 + sl;
  const int bfrag = (wc + (lane & 15)) * 32 + sl;

  for (int ks = 0; ks < 32; ++ks) {
    const int buf = ks & 1;
    __syncthreads();
    if (ks + 1 < 32) {
      const int k1 = (ks + 1) << 5;
      gload16(ap0 + k1, (char*)sA[buf ^ 1] + ldsoff);
      gload16(ap1 + k1, (char*)sA[buf ^ 1] + 4096 + ldsoff);
      gload16(ap2 + k1, (char*)sA[buf ^ 1] + 8192 + ldsoff);
      gload16(ap3 + k1, (char*)sA[buf ^ 1] + 12288 + ldsoff);
      gload16(bp0 + k1, (char*)sB[buf ^ 1] + ldsoff);
      gload16(bp1 + k1, (char*)sB[buf ^ 1] + 4096 + ldsoff);
    }
    bf16x8 av[8], bv[4];
#pragma unroll
    for (int f = 0; f < 8; ++f) av[f] = *(const bf16x8*)&sA[buf][afrag + f * 512];
#pragma unroll
    for (int f = 0; f < 4; ++f) bv[f] = *(const bf16x8*)&sB[buf][bfrag + f * 512];
#pragma unroll
    for (int i = 0; i < 8; ++i)
#pragma unroll
      for (int j = 0; j < 4; ++j)
        acc[i][j] = __builtin_amdgcn_mfma_f32_16x16x32_bf16(av[i], bv[j], acc[i][j], 0, 0, 0);
  }

  const int lc = lane & 15;
  const int lr4 = (lane >> 4) << 2;
#pragma unroll
  for (int j = 0; j < 4; ++j) {
    const int c = (jt << 7) + wc + (j << 4) + lc;
    const float bias = (c < 1024) ? eb1[(e << 10) + c] : ub1[c - 1024];
#pragma unroll
    for (int i = 0; i < 8; ++i) {
      const int rl = wr + (i << 4) + lr4;
#pragma unroll
      for (int q = 0; q < 4; ++q) {
        const int p = row0 + rl + q;
        if (p < gend) hid[((size_t)p << 11) + c] = f2bf(fmaxf(acc[i][j][q] + bias, 0.f));
      }
    }
  }
}

// ---------------- GEMM2: 256x128 tile, per-wave 128x64, K=2048 ----------------
__global__ __launch_bounds__(256) void gemm2_kernel(
    const u16* __restrict__ hid, const u16* __restrict__ ew2t,
    const u16* __restrict__ uw2t, const float* __restrict__ eb2,
    const float* __restrict__ ub2, const int* __restrict__ meta,
    const int* __restrict__ perm, float* __restrict__ out) {
  const int nt = meta[25];
  // grid 576 = 8 * 72 (XCD-bijective), mt-major: 72 mt x 8 jt
  const int pb = blockIdx.x;
  const int L = (pb & 7) * 72 + (pb >> 3);
  const int mt = L >> 3;
  const int jt = L & 7;
  if (mt >= nt) return;
  const int e = meta[32 + mt], row0 = meta[192 + mt], gend = meta[352 + mt];
  const int n0 = jt << 7;

  __shared__ u16 sA[2][256 * 32];
  __shared__ u16 sB[2][128 * 32];

  const int tid = threadIdx.x;
  const int lane = tid & 63;
  const int wave = tid >> 6;
  const int wr = (wave >> 1) << 7;
  const int wc = (wave & 1) << 6;

  const int smrow = tid >> 2;
  const int skoff = (((tid & 3) ^ ((tid >> 3) & 3)) << 3);
  int r0c = row0 + smrow;       if (r0c > NTOK - 1) r0c = NTOK - 1;
  int r1c = row0 + smrow + 64;  if (r1c > NTOK - 1) r1c = NTOK - 1;
  int r2c = row0 + smrow + 128; if (r2c > NTOK - 1) r2c = NTOK - 1;
  int r3c = row0 + smrow + 192; if (r3c > NTOK - 1) r3c = NTOK - 1;
  const u16* ap0 = hid + (((size_t)r0c) << 11) + skoff;
  const u16* ap1 = hid + (((size_t)r1c) << 11) + skoff;
  const u16* ap2 = hid + (((size_t)r2c) << 11) + skoff;
  const u16* ap3 = hid + (((size_t)r3c) << 11) + skoff;
  const u16* ebase = ew2t + ((size_t)e << 20);
  const size_t brow0 = (((size_t)(n0 + smrow)) << 10) + skoff;
  const size_t brow1 = (((size_t)(n0 + smrow + 64)) << 10) + skoff;
  const int ldsoff = wave << 10;

  f32x4 acc[8][4];
#pragma unroll
  for (int i = 0; i < 8; ++i)
#pragma unroll
    for (int j = 0; j < 4; ++j) acc[i][j] = (f32x4){0.f, 0.f, 0.f, 0.f};

  gload16(ap0, (char*)sA[0] + ldsoff);
  gload16(ap1, (char*)sA[0] + 4096 + ldsoff);
  gload16(ap2, (char*)sA[0] + 8192 + ldsoff);
  gload16(ap3, (char*)sA[0] + 12288 + ldsoff);
  gload16(ebase + brow0, (char*)sB[0] + ldsoff);
  gload16(ebase + brow1, (char*)sB[0] + 4096 + ldsoff);

  const int sl = (((lane >> 4) ^ ((lane >> 1) & 3)) << 3);
  const int afrag = (wr + (lane & 15)) * 32 + sl;
  const int bfrag = (wc + (lane & 15)) * 32 + sl;

  for (int ks = 0; ks < 64; ++ks) {
    const int buf = ks & 1;
    __syncthreads();
    if (ks + 1 < 64) {
      const int k1 = (ks + 1) << 5;
      const u16* bb = (k1 < 1024) ? ebase : uw2t;
      const int kk = k1 & 1023;
      gload16(ap0 + k1, (char*)sA[buf ^ 1] + ldsoff);
      gload16(ap1 + k1, (char*)sA[buf ^ 1] + 4096 + ldsoff);
      gload16(ap2 + k1, (char*)sA[buf ^ 1] + 8192 + ldsoff);
      gload16(ap3 + k1, (char*)sA[buf ^ 1] + 12288 + ldsoff);
      gload16(bb + brow0 + kk, (char*)sB[buf ^ 1] + ldsoff);
      gload16(bb + brow1 + kk, (char*)sB[buf ^ 1] + 4096 + ldsoff);
    }
    bf16x8 av[8], bv[4];
#pragma unroll
    for (int f = 0; f < 8; ++f) av[f] = *(const bf16x8*)&sA[buf][afrag + f * 512];
#pragma unroll
    for (int f = 0; f < 4; ++f) bv[f] = *(const bf16x8*)&sB[buf][bfrag + f * 512];
#pragma unroll
    for (int i = 0; i < 8; ++i)
#pragma unroll
      for (int j = 0; j < 4; ++j)
        acc[i][j] = __builtin_amdgcn_mfma_f32_16x16x32_bf16(av[i], bv[j], acc[i][j], 0, 0, 0);
  }

  const int lc = lane & 15;
  const int lr4 = (lane >> 4) << 2;
#pragma unroll
  for (int j = 0; j < 4; ++j) {
    const int c = n0 + wc + (j << 4) + lc;
    const float bias = eb2[(e << 10) + c] + ub2[c];
#pragma unroll
    for (int i = 0; i < 8; ++i) {
      const int rl = wr + (i << 4) + lr4;
#pragma unroll
      for (int q = 0; q < 4; ++q) {
        const int p = row0 + rl + q;
        if (p < gend) out[((size_t)perm[p] << 10) + c] = acc[i][j][q] + bias;
      }
    }
  }
}

extern "C" void kernel_launch(void* const* d_in, const int* in_sizes, int n_in,
                              void* d_out, int out_size, void* d_ws, size_t ws_size,
                              hipStream_t stream) {
  const float* x   = (const float*)d_in[0];
  const float* ue  = (const float*)d_in[1];
  const float* sw1 = (const float*)d_in[2];
  const float* sb1 = (const float*)d_in[3];
  const float* sw2 = (const float*)d_in[4];
  const float* sb2 = (const float*)d_in[5];
  const float* ew1 = (const float*)d_in[6];
  const float* eb1 = (const float*)d_in[7];
  const float* ew2 = (const float*)d_in[8];
  const float* eb2 = (const float*)d_in[9];
  const float* uw1 = (const float*)d_in[10];
  const float* ub1 = (const float*)d_in[11];
  const float* uw2 = (const float*)d_in[12];
  const float* ub2 = (const float*)d_in[13];
  float* out = (float*)d_out;

  char* w = (char*)d_ws;
  int* meta = (int*)w;    w += 4096;
  int* routes = (int*)w;  w += NTOK * 4;
  int* perm = (int*)w;    w += NTOK * 4;
  char* region = w;
  u16* xg   = (u16*)region;                                             // 33,816,576 B
  u16* ew1t = (u16*)(region + 33816576ull);                             // 16 MiB
  u16* ew2t = (u16*)(region + 33816576ull + 16777216ull);               // 16 MiB
  u16* uw1t = (u16*)(region + 33816576ull + 2 * 16777216ull);           // 2 MiB
  u16* uw2t = (u16*)(region + 33816576ull + 2 * 16777216ull + 2097152ull);
  u16* hid  = (u16*)(region + 33816576ull + 2 * 16777216ull + 2 * 2097152ull);  // 67,633,152 B
  const size_t region_sz = 33816576ull + 2 * 16777216ull + 2 * 2097152ull + 67633152ull;
  // router-phase aliases live in the (dead-until-gemm1) hid region / xg region:
  _Float16* aP     = (_Float16*)(region + 33816576ull + 2 * 16777216ull + 2 * 2097152ull);
  float* hidden32  = (float*)region;
  _Float16* bP     = (_Float16*)(region + 16777216ull);
  if (135168ull + region_sz > ws_size) return;

  hipMemsetAsync(meta, 0, 4096, stream);
  prep_kernel<<<12864, 256, 0, stream>>>(ue, aP, sw1, bP, ew1, ew2, uw1, uw2,
                                         ew1t, ew2t, uw1t, uw2t);
  rgemm_kernel<<<512, 256, 0, stream>>>(aP, bP, sb1, hidden32);
  logits_kernel<<<NTOK / 32, 256, 0, stream>>>(hidden32, sw2, sb2, routes, meta);
  scan_kernel<<<1, 64, 0, stream>>>(meta);
  perm_kernel<<<NTOK / 256, 256, 0, stream>>>(routes, meta, perm);
  gatherx_kernel<<<(NTOK * 128) / 256, 256, 0, stream>>>(x, perm, xg);
  gemm1_kernel<<<1152, 256, 0, stream>>>(xg, ew1t, uw1t, eb1, ub1, meta, hid);
  gemm2_kernel<<<576, 256, 0, stream>>>(hid, ew2t, uw2t, eb2, ub2, meta, perm, out);
}

// Round 7
// 675.773 us; speedup vs baseline: 1.1468x; 1.1468x over previous
//
#include <hip/hip_runtime.h>
#include <stdint.h>

#define NTOK 16384
#define HD   1024
#define SD   256
#define NE   8

typedef short bf16x8 __attribute__((ext_vector_type(8)));
typedef _Float16 f16x8 __attribute__((ext_vector_type(8)));
typedef float f32x4 __attribute__((ext_vector_type(4)));
typedef unsigned short u16;
typedef unsigned short u16x8 __attribute__((ext_vector_type(8)));

__device__ __forceinline__ u16 f2bf(float f) {
  union { float f; unsigned u; } v; v.f = f;
  return (u16)((v.u + 0x7fffu + ((v.u >> 16) & 1u)) >> 16);
}

__device__ __forceinline__ void gload16(const void* g, void* l) {
  __builtin_amdgcn_global_load_lds((const __attribute__((address_space(1))) void*)g,
                                   (__attribute__((address_space(3))) void*)l,
                                   16, 0, 0);
}

#define VMC(N) asm volatile("s_waitcnt vmcnt(" #N ")" ::: "memory")
#define BARRAW __builtin_amdgcn_s_barrier()
#define SCHED0 __builtin_amdgcn_sched_barrier(0)

// meta layout (ints): [0..7] counts, [8..15] cursors, [16..24] offsets,
// [25] ntiles, [32..191] tile_e, [192..351] tile_row0, [352..511] tile_end

// LDS chunk-XOR swizzle (all 3 GEMMs): tile rows are 32 u16 = 4 chunks of 16B.
// LDS[row][slot] holds global chunk (slot ^ ((row>>1)&3)). Staging lane l reads
// global chunk (l&3)^((l>>3)&3) of row l>>2 -> each 4-lane group still covers
// one contiguous 64B row segment (VMEM coalescing identical) and the linear
// gload_lds dest produces the swizzled layout. Fragment read lane l uses slot
// (l>>4)^((l>>1)&3): conflict-free ds_read_b128 (verified: conflicts 8.7M -> 0).
//
// gemm1/gemm2 use TRIPLE-buffered LDS + raw s_barrier + counted vmcnt:
// per K-step t: VMC(4) [tile-t loads landed; t+1 stays in flight], BAR, then
// issue tile t+2 into buf (t+2)%3, then read buf t%3 + 16 MFMA. Loads get
// 2 K-steps (~1300 cyc) of lead > HBM latency; fresh loads never drained
// (removes the __syncthreads vmcnt(0) per-step drain stall).

// ---------------- Fused prep: aprep (8192 blk) + bprep (64 blk) + tconv (4608 blk) ----------------
__global__ __launch_bounds__(256) void prep_kernel(
    const float* __restrict__ ue, _Float16* __restrict__ aP,
    const float* __restrict__ sw1, _Float16* __restrict__ bP,
    const float* __restrict__ ew1, const float* __restrict__ ew2,
    const float* __restrict__ uw1, const float* __restrict__ uw2,
    u16* __restrict__ ew1t, u16* __restrict__ ew2t,
    u16* __restrict__ uw1t, u16* __restrict__ uw2t) {
  const int bid = blockIdx.x;
  const int tid = threadIdx.x;
  if (bid < 8192) {
    // --- aprep: ue f32 -> A' = [hi | lo] fp16, row stride 2048 ---
    const int t = bid * 256 + tid;
    const int p = t >> 7;
    const int h = (t & 127) << 3;
    const float* s = ue + ((size_t)p << 10) + h;
    const float4 a = *(const float4*)s;
    const float4 b = *(const float4*)(s + 4);
    float v[8] = {a.x, a.y, a.z, a.w, b.x, b.y, b.z, b.w};
    f16x8 hi, lo;
#pragma unroll
    for (int j = 0; j < 8; ++j) {
      const _Float16 h16 = (_Float16)v[j];
      hi[j] = h16;
      lo[j] = (_Float16)(v[j] - (float)h16);
    }
    _Float16* d = aP + ((size_t)p << 11) + h;
    *(f16x8*)d = hi;
    *(f16x8*)(d + 1024) = lo;
    return;
  }
  __shared__ float tb[64][65];
  if (bid < 8256) {
    // --- bprep: sw1 [1024][256] f32 -> B' [256][3072] fp16 = [hi|lo|hi] ---
    const int b = bid - 8192;
    const int c0 = (b & 3) << 6;
    const int r0 = (b >> 2) << 6;
    {
      const int lr = tid >> 2, q = (tid & 3) << 4;
      const float* s = sw1 + (size_t)(r0 + lr) * SD + c0 + q;
#pragma unroll
      for (int j = 0; j < 16; j += 4) {
        const float4 v = *(const float4*)(s + j);
        tb[lr][q + j] = v.x; tb[lr][q + j + 1] = v.y;
        tb[lr][q + j + 2] = v.z; tb[lr][q + j + 3] = v.w;
      }
    }
    __syncthreads();
    const int lc = tid >> 2, rq = (tid & 3) << 4;
    f16x8 hi0, hi1, lo0, lo1;
#pragma unroll
    for (int j = 0; j < 8; ++j) {
      const float v0 = tb[rq + j][lc];
      const _Float16 h0 = (_Float16)v0;
      hi0[j] = h0; lo0[j] = (_Float16)(v0 - (float)h0);
      const float v1 = tb[rq + 8 + j][lc];
      const _Float16 h1 = (_Float16)v1;
      hi1[j] = h1; lo1[j] = (_Float16)(v1 - (float)h1);
    }
    _Float16* d = bP + (size_t)(c0 + lc) * 3072 + r0 + rq;
    *(f16x8*)d = hi0;           *(f16x8*)(d + 8) = hi1;
    *(f16x8*)(d + 1024) = lo0;  *(f16x8*)(d + 1032) = lo1;
    *(f16x8*)(d + 2048) = hi0;  *(f16x8*)(d + 2056) = hi1;
    return;
  }
  // --- tconv: transpose+convert 1024x1024 f32 -> bf16, 18 matrices ---
  const int c = bid - 8256;
  const int m = c >> 8;
  const int t2 = c & 255;
  const int c0 = (t2 & 15) << 6;
  const int r0 = (t2 >> 4) << 6;
  const size_t msz = (size_t)HD * HD;
  const float* src; u16* dst;
  if (m < 8)       { src = ew1 + (size_t)m * msz;       dst = ew1t + (size_t)m * msz; }
  else if (m < 16) { src = ew2 + (size_t)(m - 8) * msz; dst = ew2t + (size_t)(m - 8) * msz; }
  else if (m == 16){ src = uw1;                          dst = uw1t; }
  else             { src = uw2;                          dst = uw2t; }
  {
    const int lr = tid >> 2, q = (tid & 3) << 4;
    const float* s = src + (size_t)(r0 + lr) * HD + c0 + q;
#pragma unroll
    for (int j = 0; j < 16; j += 4) {
      const float4 v = *(const float4*)(s + j);
      tb[lr][q + j] = v.x; tb[lr][q + j + 1] = v.y;
      tb[lr][q + j + 2] = v.z; tb[lr][q + j + 3] = v.w;
    }
  }
  __syncthreads();
  {
    const int lc = tid >> 2, rq = (tid & 3) << 4;
    u16x8 o0, o1;
#pragma unroll
    for (int j = 0; j < 8; ++j) o0[j] = f2bf(tb[rq + j][lc]);
#pragma unroll
    for (int j = 0; j < 8; ++j) o1[j] = f2bf(tb[rq + 8 + j][lc]);
    u16* d = dst + (size_t)(c0 + lc) * HD + r0 + rq;
    *(u16x8*)d = o0;
    *(u16x8*)(d + 8) = o1;
  }
}

// ---------------- Router GEMM: hidden[p][s] = relu(3-term hi/lo fp16 MFMA + sb1), f32 out ----------------
__global__ __launch_bounds__(256) void rgemm_kernel(
    const _Float16* __restrict__ aP, const _Float16* __restrict__ bP,
    const float* __restrict__ sb1, float* __restrict__ hidden) {
  const int p = blockIdx.x;
  const int L = (p & 7) * 64 + (p >> 3);
  const int jt = L & 3;           // 64-col tile
  const int row0 = (L >> 2) << 7; // 128-row tile

  __shared__ _Float16 sA[2][128 * 32];
  __shared__ _Float16 sB[2][64 * 32];

  const int tid = threadIdx.x, lane = tid & 63, wave = tid >> 6;
  const int wr = (wave >> 1) << 6, wc = (wave & 1) << 5;
  const int smrow = tid >> 2, skoff = (((tid & 3) ^ ((tid >> 3) & 3)) << 3);
  const _Float16* ar0 = aP + ((size_t)(row0 + smrow) << 11) + skoff;
  const _Float16* ar1 = aP + ((size_t)(row0 + smrow + 64) << 11) + skoff;
  const _Float16* br  = bP + (size_t)((jt << 6) + smrow) * 3072 + skoff;
  const int ldsoff = wave << 10;

  f32x4 acc[4][2];
#pragma unroll
  for (int i = 0; i < 4; ++i)
#pragma unroll
    for (int j = 0; j < 2; ++j) acc[i][j] = (f32x4){0.f, 0.f, 0.f, 0.f};

  gload16(ar0, (char*)sA[0] + ldsoff);
  gload16(ar1, (char*)sA[0] + 4096 + ldsoff);
  gload16(br,  (char*)sB[0] + ldsoff);

  const int sl = (((lane >> 4) ^ ((lane >> 1) & 3)) << 3);
  const int afrag = (wr + (lane & 15)) * 32 + sl;
  const int bfrag = (wc + (lane & 15)) * 32 + sl;

  for (int ks = 0; ks < 96; ++ks) {
    const int buf = ks & 1;
    __syncthreads();
    if (ks + 1 < 96) {
      const int k1 = ks + 1;
      const int pa = (k1 < 64) ? ((k1 & 31) << 5) : (1024 + ((k1 - 64) << 5));
      gload16(ar0 + pa, (char*)sA[buf ^ 1] + ldsoff);
      gload16(ar1 + pa, (char*)sA[buf ^ 1] + 4096 + ldsoff);
      gload16(br + (k1 << 5), (char*)sB[buf ^ 1] + ldsoff);
    }
    f16x8 av[4], bv[2];
#pragma unroll
    for (int f = 0; f < 4; ++f) av[f] = *(const f16x8*)&sA[buf][afrag + f * 512];
#pragma unroll
    for (int f = 0; f < 2; ++f) bv[f] = *(const f16x8*)&sB[buf][bfrag + f * 512];
#pragma unroll
    for (int i = 0; i < 4; ++i)
#pragma unroll
      for (int j = 0; j < 2; ++j)
        acc[i][j] = __builtin_amdgcn_mfma_f32_16x16x32_f16(av[i], bv[j], acc[i][j], 0, 0, 0);
  }

  const int lc = lane & 15, lr4 = (lane >> 4) << 2;
#pragma unroll
  for (int j = 0; j < 2; ++j) {
    const int c = (jt << 6) + wc + (j << 4) + lc;
    const float bias = sb1[c];
#pragma unroll
    for (int i = 0; i < 4; ++i) {
      const int rl = wr + (i << 4) + lr4;
#pragma unroll
      for (int q = 0; q < 4; ++q)
        hidden[((size_t)(row0 + rl + q) << 8) + c] = fmaxf(acc[i][j][q] + bias, 0.f);
    }
  }
}

// ---------------- Logits layer-2 (f32, fixed order) + argmax + histogram ----------------
__global__ __launch_bounds__(256) void logits_kernel(
    const float* __restrict__ hidden, const float* __restrict__ sw2,
    const float* __restrict__ sb2, int* __restrict__ routes, int* meta) {
  __shared__ float logl[32][8];
  const int tid = threadIdx.x;
  const int tok0 = blockIdx.x << 5;
  const int tl = tid >> 3, e2 = tid & 7;
  const float* hp = hidden + ((size_t)(tok0 + tl) << 8);
  float a0 = 0.f, a1 = 0.f, a2 = 0.f, a3 = 0.f;
  for (int q = 0; q < SD; q += 8) {
    const float4 h0 = *(const float4*)&hp[q];
    const float4 h1 = *(const float4*)&hp[q + 4];
    a0 = fmaf(h0.x, sw2[((q + 0) << 3) + e2], a0);
    a1 = fmaf(h0.y, sw2[((q + 1) << 3) + e2], a1);
    a2 = fmaf(h0.z, sw2[((q + 2) << 3) + e2], a2);
    a3 = fmaf(h0.w, sw2[((q + 3) << 3) + e2], a3);
    a0 = fmaf(h1.x, sw2[((q + 4) << 3) + e2], a0);
    a1 = fmaf(h1.y, sw2[((q + 5) << 3) + e2], a1);
    a2 = fmaf(h1.z, sw2[((q + 6) << 3) + e2], a2);
    a3 = fmaf(h1.w, sw2[((q + 7) << 3) + e2], a3);
  }
  logl[tl][e2] = (a0 + a1) + (a2 + a3) + sb2[e2];
  __syncthreads();
  if (tid < 32) {
    float best = logl[tid][0]; int be = 0;
#pragma unroll
    for (int e = 1; e < 8; ++e) {
      const float v = logl[tid][e];
      if (v > best) { best = v; be = e; }
    }
    routes[tok0 + tid] = be;
    atomicAdd(&meta[be], 1);
  }
}

// ---------------- Scan: offsets + tile table (128-row tiles) ----------------
__global__ void scan_kernel(int* meta) {
  if (threadIdx.x != 0) return;
  int off = 0;
  for (int e = 0; e < NE; ++e) { meta[16 + e] = off; off += meta[e]; }
  meta[24] = off;
  int nt = 0;
  for (int e = 0; e < NE; ++e) {
    const int s = meta[16 + e], en = meta[16 + e + 1];
    for (int r0 = s; r0 < en; r0 += 128) {
      meta[32 + nt] = e; meta[192 + nt] = r0; meta[352 + nt] = en; ++nt;
    }
  }
  meta[25] = nt;
}

// ---------------- Build permutation (token -> grouped position) ----------------
__global__ void perm_kernel(const int* __restrict__ routes, int* meta, int* __restrict__ perm) {
  const int b = blockIdx.x * 256 + threadIdx.x;
  const int r = routes[b];
  const int pos = meta[16 + r] + atomicAdd(&meta[8 + r], 1);
  perm[pos] = b;
}

// ---------------- Gather x rows into grouped order, f32 -> bf16 ----------------
__global__ __launch_bounds__(256) void gatherx_kernel(
    const float* __restrict__ x, const int* __restrict__ perm, u16* __restrict__ xg) {
  const int t = blockIdx.x * 256 + threadIdx.x;
  const int p = t >> 7;
  const int j = (t & 127) << 3;
  const int tok = perm[p];
  const float* s = &x[((size_t)tok << 10) + j];
  const float4 a = *(const float4*)s;
  const float4 b = *(const float4*)(s + 4);
  u16x8 o;
  o[0] = f2bf(a.x); o[1] = f2bf(a.y); o[2] = f2bf(a.z); o[3] = f2bf(a.w);
  o[4] = f2bf(b.x); o[5] = f2bf(b.y); o[6] = f2bf(b.z); o[7] = f2bf(b.w);
  *(u16x8*)&xg[((size_t)p << 10) + j] = o;
}

// ---------------- GEMM1: hid[p][0:2048] = relu(xg[p] @ [ew1[e] | uw1] + eb1[e]/ub1) ----------------
__global__ __launch_bounds__(256) void gemm1_kernel(
    const u16* __restrict__ xg, const u16* __restrict__ ew1t,
    const u16* __restrict__ uw1t, const float* __restrict__ eb1,
    const float* __restrict__ ub1, const int* __restrict__ meta,
    u16* __restrict__ hid) {
  const int nt = meta[25];
  // XCD-chunked, mt-major: grid 2160 = 16 jt x 135 mt
  const int pb = blockIdx.x;
  const int L = (pb & 7) * 270 + (pb >> 3);
  const int mt = L >> 4;
  const int jt = L & 15;
  if (mt >= nt) return;
  const int e = meta[32 + mt], row0 = meta[192 + mt], gend = meta[352 + mt];
  const u16* wbase = (jt < 8)
      ? ew1t + ((size_t)e << 20) + ((size_t)(jt << 7) << 10)
      : uw1t + ((size_t)((jt - 8) << 7) << 10);

  __shared__ u16 sA[3][128 * 32];
  __shared__ u16 sB[3][128 * 32];

  const int tid = threadIdx.x;
  const int lane = tid & 63;
  const int wave = tid >> 6;
  const int wr = (wave >> 1) << 6;
  const int wc = (wave & 1) << 6;

  const int smrow = tid >> 2;
  const int skoff = (((tid & 3) ^ ((tid >> 3) & 3)) << 3);
  const u16* ap0 = xg + (((size_t)(row0 + smrow)) << 10) + skoff;
  const u16* ap1 = xg + (((size_t)(row0 + smrow + 64)) << 10) + skoff;
  const u16* bp0 = wbase + (((size_t)smrow) << 10) + skoff;
  const u16* bp1 = wbase + (((size_t)(smrow + 64)) << 10) + skoff;
  const int ldsoff = wave << 10;

  f32x4 acc[4][4];
#pragma unroll
  for (int i = 0; i < 4; ++i)
#pragma unroll
    for (int j = 0; j < 4; ++j) acc[i][j] = (f32x4){0.f, 0.f, 0.f, 0.f};

  // prologue: tiles 0 -> buf0, 1 -> buf1 (8 loads in flight)
  gload16(ap0,      (char*)sA[0] + ldsoff);
  gload16(ap1,      (char*)sA[0] + 4096 + ldsoff);
  gload16(bp0,      (char*)sB[0] + ldsoff);
  gload16(bp1,      (char*)sB[0] + 4096 + ldsoff);
  gload16(ap0 + 32, (char*)sA[1] + ldsoff);
  gload16(ap1 + 32, (char*)sA[1] + 4096 + ldsoff);
  gload16(bp0 + 32, (char*)sB[1] + ldsoff);
  gload16(bp1 + 32, (char*)sB[1] + 4096 + ldsoff);

  const int sl = (((lane >> 4) ^ ((lane >> 1) & 3)) << 3);
  const int afrag = (wr + (lane & 15)) * 32 + sl;
  const int bfrag = (wc + (lane & 15)) * 32 + sl;

#define G1_STEP(RB, WB, T2, DOI, N) do { \
  VMC(N); BARRAW; SCHED0; \
  if (DOI) { \
    const int kk_ = (T2) << 5; \
    gload16(ap0 + kk_, (char*)sA[WB] + ldsoff); \
    gload16(ap1 + kk_, (char*)sA[WB] + 4096 + ldsoff); \
    gload16(bp0 + kk_, (char*)sB[WB] + ldsoff); \
    gload16(bp1 + kk_, (char*)sB[WB] + 4096 + ldsoff); \
  } \
  bf16x8 av_[4], bv_[4]; \
  _Pragma("unroll") \
  for (int f_ = 0; f_ < 4; ++f_) { \
    av_[f_] = *(const bf16x8*)&sA[RB][afrag + f_ * 512]; \
    bv_[f_] = *(const bf16x8*)&sB[RB][bfrag + f_ * 512]; \
  } \
  _Pragma("unroll") \
  for (int i_ = 0; i_ < 4; ++i_) \
    _Pragma("unroll") \
    for (int j_ = 0; j_ < 4; ++j_) \
      acc[i_][j_] = __builtin_amdgcn_mfma_f32_16x16x32_bf16(av_[i_], bv_[j_], acc[i_][j_], 0, 0, 0); \
} while (0)

  {
    int t = 0;
    for (int i = 0; i < 10; ++i) {        // t = 0..29, issue t+2
      G1_STEP(0, 2, t + 2, 1, 4); ++t;
      G1_STEP(1, 0, t + 2, 1, 4); ++t;
      G1_STEP(2, 1, t + 2, 1, 4); ++t;
    }
    G1_STEP(0, 0, 0, 0, 4);               // t = 30 (tile 31 still in flight)
    G1_STEP(1, 0, 0, 0, 0);               // t = 31
  }
#undef G1_STEP

  const int lc = lane & 15;
  const int lr4 = (lane >> 4) << 2;
#pragma unroll
  for (int j = 0; j < 4; ++j) {
    const int c = (jt << 7) + wc + (j << 4) + lc;
    const float bias = (c < 1024) ? eb1[(e << 10) + c] : ub1[c - 1024];
#pragma unroll
    for (int i = 0; i < 4; ++i) {
      const int rl = wr + (i << 4) + lr4;
#pragma unroll
      for (int q = 0; q < 4; ++q) {
        const int p = row0 + rl + q;
        if (p < gend) hid[((size_t)p << 11) + c] = f2bf(fmaxf(acc[i][j][q] + bias, 0.f));
      }
    }
  }
}

// ---------------- GEMM2: out[perm[p]][c] = hid[p] @ [ew2[e]; uw2] + eb2[e] + ub2 ----------------
__global__ __launch_bounds__(256) void gemm2_kernel(
    const u16* __restrict__ hid, const u16* __restrict__ ew2t,
    const u16* __restrict__ uw2t, const float* __restrict__ eb2,
    const float* __restrict__ ub2, const int* __restrict__ meta,
    const int* __restrict__ perm, float* __restrict__ out) {
  const int nt = meta[25];
  // XCD-chunked, mt-major: grid 1080 = 8 jt x 135 mt
  const int pb = blockIdx.x;
  const int L = (pb & 7) * 135 + (pb >> 3);
  const int mt = L >> 3;
  const int jt = L & 7;
  if (mt >= nt) return;
  const int e = meta[32 + mt], row0 = meta[192 + mt], gend = meta[352 + mt];
  const int n0 = jt << 7;

  __shared__ u16 sA[3][128 * 32];
  __shared__ u16 sB[3][128 * 32];

  const int tid = threadIdx.x;
  const int lane = tid & 63;
  const int wave = tid >> 6;
  const int wr = (wave >> 1) << 6;
  const int wc = (wave & 1) << 6;

  const int smrow = tid >> 2;
  const int skoff = (((tid & 3) ^ ((tid >> 3) & 3)) << 3);
  const u16* ap0 = hid + (((size_t)(row0 + smrow)) << 11) + skoff;
  const u16* ap1 = hid + (((size_t)(row0 + smrow + 64)) << 11) + skoff;
  const u16* ebase = ew2t + ((size_t)e << 20);
  const size_t brow0 = (((size_t)(n0 + smrow)) << 10) + skoff;
  const size_t brow1 = (((size_t)(n0 + smrow + 64)) << 10) + skoff;
  const int ldsoff = wave << 10;

  f32x4 acc[4][4];
#pragma unroll
  for (int i = 0; i < 4; ++i)
#pragma unroll
    for (int j = 0; j < 4; ++j) acc[i][j] = (f32x4){0.f, 0.f, 0.f, 0.f};

  // prologue: tiles 0 -> buf0, 1 -> buf1
  gload16(ap0,              (char*)sA[0] + ldsoff);
  gload16(ap1,              (char*)sA[0] + 4096 + ldsoff);
  gload16(ebase + brow0,    (char*)sB[0] + ldsoff);
  gload16(ebase + brow1,    (char*)sB[0] + 4096 + ldsoff);
  gload16(ap0 + 32,         (char*)sA[1] + ldsoff);
  gload16(ap1 + 32,         (char*)sA[1] + 4096 + ldsoff);
  gload16(ebase + brow0 + 32, (char*)sB[1] + ldsoff);
  gload16(ebase + brow1 + 32, (char*)sB[1] + 4096 + ldsoff);

  const int sl = (((lane >> 4) ^ ((lane >> 1) & 3)) << 3);
  const int afrag = (wr + (lane & 15)) * 32 + sl;
  const int bfrag = (wc + (lane & 15)) * 32 + sl;

#define G2_STEP(RB, WB, T2, DOI, N) do { \
  VMC(N); BARRAW; SCHED0; \
  if (DOI) { \
    const int tt_ = (T2); \
    const u16* bb_ = (tt_ < 32) ? ebase : uw2t; \
    const int kb_ = (tt_ & 31) << 5; \
    const int ka_ = tt_ << 5; \
    gload16(ap0 + ka_, (char*)sA[WB] + ldsoff); \
    gload16(ap1 + ka_, (char*)sA[WB] + 4096 + ldsoff); \
    gload16(bb_ + brow0 + kb_, (char*)sB[WB] + ldsoff); \
    gload16(bb_ + brow1 + kb_, (char*)sB[WB] + 4096 + ldsoff); \
  } \
  bf16x8 av_[4], bv_[4]; \
  _Pragma("unroll") \
  for (int f_ = 0; f_ < 4; ++f_) { \
    av_[f_] = *(const bf16x8*)&sA[RB][afrag + f_ * 512]; \
    bv_[f_] = *(const bf16x8*)&sB[RB][bfrag + f_ * 512]; \
  } \
  _Pragma("unroll") \
  for (int i_ = 0; i_ < 4; ++i_) \
    _Pragma("unroll") \
    for (int j_ = 0; j_ < 4; ++j_) \
      acc[i_][j_] = __builtin_amdgcn_mfma_f32_16x16x32_bf16(av_[i_], bv_[j_], acc[i_][j_], 0, 0, 0); \
} while (0)

  {
    int t = 0;
    for (int i = 0; i < 20; ++i) {        // t = 0..59, issue t+2
      G2_STEP(0, 2, t + 2, 1, 4); ++t;
      G2_STEP(1, 0, t + 2, 1, 4); ++t;
      G2_STEP(2, 1, t + 2, 1, 4); ++t;
    }
    G2_STEP(0, 2, t + 2, 1, 4); ++t;      // t = 60, issue 62
    G2_STEP(1, 0, t + 2, 1, 4); ++t;      // t = 61, issue 63
    G2_STEP(2, 0, 0, 0, 4);               // t = 62 (tile 63 in flight)
    G2_STEP(0, 0, 0, 0, 0);               // t = 63
  }
#undef G2_STEP

  const int lc = lane & 15;
  const int lr4 = (lane >> 4) << 2;
#pragma unroll
  for (int j = 0; j < 4; ++j) {
    const int c = n0 + wc + (j << 4) + lc;
    const float bias = eb2[(e << 10) + c] + ub2[c];
#pragma unroll
    for (int i = 0; i < 4; ++i) {
      const int rl = wr + (i << 4) + lr4;
#pragma unroll
      for (int q = 0; q < 4; ++q) {
        const int p = row0 + rl + q;
        if (p < gend) out[((size_t)perm[p] << 10) + c] = acc[i][j][q] + bias;
      }
    }
  }
}

extern "C" void kernel_launch(void* const* d_in, const int* in_sizes, int n_in,
                              void* d_out, int out_size, void* d_ws, size_t ws_size,
                              hipStream_t stream) {
  const float* x   = (const float*)d_in[0];
  const float* ue  = (const float*)d_in[1];
  const float* sw1 = (const float*)d_in[2];
  const float* sb1 = (const float*)d_in[3];
  const float* sw2 = (const float*)d_in[4];
  const float* sb2 = (const float*)d_in[5];
  const float* ew1 = (const float*)d_in[6];
  const float* eb1 = (const float*)d_in[7];
  const float* ew2 = (const float*)d_in[8];
  const float* eb2 = (const float*)d_in[9];
  const float* uw1 = (const float*)d_in[10];
  const float* ub1 = (const float*)d_in[11];
  const float* uw2 = (const float*)d_in[12];
  const float* ub2 = (const float*)d_in[13];
  float* out = (float*)d_out;

  char* w = (char*)d_ws;
  int* meta = (int*)w;    w += 4096;
  int* routes = (int*)w;  w += NTOK * 4;
  int* perm = (int*)w;    w += NTOK * 4;
  char* region = w;
  u16* xg   = (u16*)region;                                             // 33,816,576 B
  u16* ew1t = (u16*)(region + 33816576ull);                             // 16 MiB
  u16* ew2t = (u16*)(region + 33816576ull + 16777216ull);               // 16 MiB
  u16* uw1t = (u16*)(region + 33816576ull + 2 * 16777216ull);           // 2 MiB
  u16* uw2t = (u16*)(region + 33816576ull + 2 * 16777216ull + 2097152ull);
  u16* hid  = (u16*)(region + 33816576ull + 2 * 16777216ull + 2 * 2097152ull);  // 67,633,152 B
  const size_t region_sz = 33816576ull + 2 * 16777216ull + 2 * 2097152ull + 67633152ull;
  // router-phase aliases live in the (dead-until-gemm1) hid region / xg region:
  _Float16* aP     = (_Float16*)(region + 33816576ull + 2 * 16777216ull + 2 * 2097152ull);
  float* hidden32  = (float*)region;
  _Float16* bP     = (_Float16*)(region + 16777216ull);
  if (135168ull + region_sz > ws_size) return;

  hipMemsetAsync(meta, 0, 4096, stream);
  prep_kernel<<<12864, 256, 0, stream>>>(ue, aP, sw1, bP, ew1, ew2, uw1, uw2,
                                         ew1t, ew2t, uw1t, uw2t);
  rgemm_kernel<<<512, 256, 0, stream>>>(aP, bP, sb1, hidden32);
  logits_kernel<<<NTOK / 32, 256, 0, stream>>>(hidden32, sw2, sb2, routes, meta);
  scan_kernel<<<1, 64, 0, stream>>>(meta);
  perm_kernel<<<NTOK / 256, 256, 0, stream>>>(routes, meta, perm);
  gatherx_kernel<<<(NTOK * 128) / 256, 256, 0, stream>>>(x, perm, xg);
  gemm1_kernel<<<2160, 256, 0, stream>>>(xg, ew1t, uw1t, eb1, ub1, meta, hid);
  gemm2_kernel<<<1080, 256, 0, stream>>>(hid, ew2t, uw2t, eb2, ub2, meta, perm, out);
}

// Round 8
// 609.697 us; speedup vs baseline: 1.2711x; 1.1084x over previous
//
#include <hip/hip_runtime.h>
#include <stdint.h>

#define NTOK 16384
#define HD   1024
#define SD   256
#define NE   8

typedef short bf16x8 __attribute__((ext_vector_type(8)));
typedef _Float16 f16x8 __attribute__((ext_vector_type(8)));
typedef float f32x4 __attribute__((ext_vector_type(4)));
typedef unsigned short u16;
typedef unsigned short u16x8 __attribute__((ext_vector_type(8)));

__device__ __forceinline__ u16 f2bf(float f) {
  union { float f; unsigned u; } v; v.f = f;
  return (u16)((v.u + 0x7fffu + ((v.u >> 16) & 1u)) >> 16);
}

__device__ __forceinline__ void gload16(const void* g, void* l) {
  __builtin_amdgcn_global_load_lds((const __attribute__((address_space(1))) void*)g,
                                   (__attribute__((address_space(3))) void*)l,
                                   16, 0, 0);
}

// meta layout (ints): [0..7] counts, [8..15] cursors, [16..24] offsets,
// [25] ntiles, [26] logits-done counter, [32..191] tile_e, [192..351] tile_row0,
// [352..511] tile_end

// LDS chunk-XOR swizzle (all 3 GEMMs): tile rows are 32 u16 = 4 chunks of 16B.
// LDS[row][slot] holds global chunk (slot ^ ((row>>1)&3)). Staging lane l reads
// global chunk (l&3)^((l>>3)&3) of row l>>2 -> each 4-lane group still covers
// one contiguous 64B row segment (VMEM coalescing identical) and the linear
// gload_lds dest produces the swizzled layout. Fragment read lane l uses slot
// (l>>4)^((l>>1)&3): conflict-free ds_read_b128 (verified: conflicts 8.7M -> 0).
//
// K-loops are FULLY UNROLLED (r7 lesson: VALUBusy 40% from runtime buf-select +
// per-step address recompute; unroll makes buf/k-offsets compile-time, folds
// global offsets into imm form). Zero LDS/VGPR structural change vs the
// 634.9us kernel.

// ---------------- Fused prep: aprep (8192 blk) + bprep (64 blk) + tconv (4608 blk) ----------------
__global__ __launch_bounds__(256) void prep_kernel(
    const float* __restrict__ ue, _Float16* __restrict__ aP,
    const float* __restrict__ sw1, _Float16* __restrict__ bP,
    const float* __restrict__ ew1, const float* __restrict__ ew2,
    const float* __restrict__ uw1, const float* __restrict__ uw2,
    u16* __restrict__ ew1t, u16* __restrict__ ew2t,
    u16* __restrict__ uw1t, u16* __restrict__ uw2t) {
  const int bid = blockIdx.x;
  const int tid = threadIdx.x;
  if (bid < 8192) {
    // --- aprep: ue f32 -> A' = [hi | lo] fp16, row stride 2048 ---
    const int t = bid * 256 + tid;
    const int p = t >> 7;
    const int h = (t & 127) << 3;
    const float* s = ue + ((size_t)p << 10) + h;
    const float4 a = *(const float4*)s;
    const float4 b = *(const float4*)(s + 4);
    float v[8] = {a.x, a.y, a.z, a.w, b.x, b.y, b.z, b.w};
    f16x8 hi, lo;
#pragma unroll
    for (int j = 0; j < 8; ++j) {
      const _Float16 h16 = (_Float16)v[j];
      hi[j] = h16;
      lo[j] = (_Float16)(v[j] - (float)h16);
    }
    _Float16* d = aP + ((size_t)p << 11) + h;
    *(f16x8*)d = hi;
    *(f16x8*)(d + 1024) = lo;
    return;
  }
  __shared__ float tb[64][65];
  if (bid < 8256) {
    // --- bprep: sw1 [1024][256] f32 -> B' [256][3072] fp16 = [hi|lo|hi] ---
    const int b = bid - 8192;
    const int c0 = (b & 3) << 6;
    const int r0 = (b >> 2) << 6;
    {
      const int lr = tid >> 2, q = (tid & 3) << 4;
      const float* s = sw1 + (size_t)(r0 + lr) * SD + c0 + q;
#pragma unroll
      for (int j = 0; j < 16; j += 4) {
        const float4 v = *(const float4*)(s + j);
        tb[lr][q + j] = v.x; tb[lr][q + j + 1] = v.y;
        tb[lr][q + j + 2] = v.z; tb[lr][q + j + 3] = v.w;
      }
    }
    __syncthreads();
    const int lc = tid >> 2, rq = (tid & 3) << 4;
    f16x8 hi0, hi1, lo0, lo1;
#pragma unroll
    for (int j = 0; j < 8; ++j) {
      const float v0 = tb[rq + j][lc];
      const _Float16 h0 = (_Float16)v0;
      hi0[j] = h0; lo0[j] = (_Float16)(v0 - (float)h0);
      const float v1 = tb[rq + 8 + j][lc];
      const _Float16 h1 = (_Float16)v1;
      hi1[j] = h1; lo1[j] = (_Float16)(v1 - (float)h1);
    }
    _Float16* d = bP + (size_t)(c0 + lc) * 3072 + r0 + rq;
    *(f16x8*)d = hi0;           *(f16x8*)(d + 8) = hi1;
    *(f16x8*)(d + 1024) = lo0;  *(f16x8*)(d + 1032) = lo1;
    *(f16x8*)(d + 2048) = hi0;  *(f16x8*)(d + 2056) = hi1;
    return;
  }
  // --- tconv: transpose+convert 1024x1024 f32 -> bf16, 18 matrices ---
  const int c = bid - 8256;
  const int m = c >> 8;
  const int t2 = c & 255;
  const int c0 = (t2 & 15) << 6;
  const int r0 = (t2 >> 4) << 6;
  const size_t msz = (size_t)HD * HD;
  const float* src; u16* dst;
  if (m < 8)       { src = ew1 + (size_t)m * msz;       dst = ew1t + (size_t)m * msz; }
  else if (m < 16) { src = ew2 + (size_t)(m - 8) * msz; dst = ew2t + (size_t)(m - 8) * msz; }
  else if (m == 16){ src = uw1;                          dst = uw1t; }
  else             { src = uw2;                          dst = uw2t; }
  {
    const int lr = tid >> 2, q = (tid & 3) << 4;
    const float* s = src + (size_t)(r0 + lr) * HD + c0 + q;
#pragma unroll
    for (int j = 0; j < 16; j += 4) {
      const float4 v = *(const float4*)(s + j);
      tb[lr][q + j] = v.x; tb[lr][q + j + 1] = v.y;
      tb[lr][q + j + 2] = v.z; tb[lr][q + j + 3] = v.w;
    }
  }
  __syncthreads();
  {
    const int lc = tid >> 2, rq = (tid & 3) << 4;
    u16x8 o0, o1;
#pragma unroll
    for (int j = 0; j < 8; ++j) o0[j] = f2bf(tb[rq + j][lc]);
#pragma unroll
    for (int j = 0; j < 8; ++j) o1[j] = f2bf(tb[rq + 8 + j][lc]);
    u16* d = dst + (size_t)(c0 + lc) * HD + r0 + rq;
    *(u16x8*)d = o0;
    *(u16x8*)(d + 8) = o1;
  }
}

// ---------------- Router GEMM: hidden[p][s] = relu(3-term hi/lo fp16 MFMA + sb1), f32 out ----------------
__global__ __launch_bounds__(256) void rgemm_kernel(
    const _Float16* __restrict__ aP, const _Float16* __restrict__ bP,
    const float* __restrict__ sb1, float* __restrict__ hidden) {
  const int p = blockIdx.x;
  const int L = (p & 7) * 64 + (p >> 3);
  const int jt = L & 3;           // 64-col tile
  const int row0 = (L >> 2) << 7; // 128-row tile

  __shared__ _Float16 sA[2][128 * 32];
  __shared__ _Float16 sB[2][64 * 32];

  const int tid = threadIdx.x, lane = tid & 63, wave = tid >> 6;
  const int wr = (wave >> 1) << 6, wc = (wave & 1) << 5;
  const int smrow = tid >> 2, skoff = (((tid & 3) ^ ((tid >> 3) & 3)) << 3);
  const _Float16* ar0 = aP + ((size_t)(row0 + smrow) << 11) + skoff;
  const _Float16* ar1 = aP + ((size_t)(row0 + smrow + 64) << 11) + skoff;
  const _Float16* br  = bP + (size_t)((jt << 6) + smrow) * 3072 + skoff;
  const int ldsoff = wave << 10;

  f32x4 acc[4][2];
#pragma unroll
  for (int i = 0; i < 4; ++i)
#pragma unroll
    for (int j = 0; j < 2; ++j) acc[i][j] = (f32x4){0.f, 0.f, 0.f, 0.f};

  gload16(ar0, (char*)sA[0] + ldsoff);
  gload16(ar1, (char*)sA[0] + 4096 + ldsoff);
  gload16(br,  (char*)sB[0] + ldsoff);

  const int sl = (((lane >> 4) ^ ((lane >> 1) & 3)) << 3);
  const int afrag = (wr + (lane & 15)) * 32 + sl;
  const int bfrag = (wc + (lane & 15)) * 32 + sl;

#pragma unroll
  for (int ks = 0; ks < 96; ++ks) {
    const int buf = ks & 1;
    __syncthreads();
    if (ks + 1 < 96) {
      const int k1 = ks + 1;
      const int pa = (k1 < 64) ? ((k1 & 31) << 5) : (1024 + ((k1 - 64) << 5));
      gload16(ar0 + pa, (char*)sA[buf ^ 1] + ldsoff);
      gload16(ar1 + pa, (char*)sA[buf ^ 1] + 4096 + ldsoff);
      gload16(br + (k1 << 5), (char*)sB[buf ^ 1] + ldsoff);
    }
    f16x8 av[4], bv[2];
#pragma unroll
    for (int f = 0; f < 4; ++f) av[f] = *(const f16x8*)&sA[buf][afrag + f * 512];
#pragma unroll
    for (int f = 0; f < 2; ++f) bv[f] = *(const f16x8*)&sB[buf][bfrag + f * 512];
#pragma unroll
    for (int i = 0; i < 4; ++i)
#pragma unroll
      for (int j = 0; j < 2; ++j)
        acc[i][j] = __builtin_amdgcn_mfma_f32_16x16x32_f16(av[i], bv[j], acc[i][j], 0, 0, 0);
  }

  const int lc = lane & 15, lr4 = (lane >> 4) << 2;
#pragma unroll
  for (int j = 0; j < 2; ++j) {
    const int c = (jt << 6) + wc + (j << 4) + lc;
    const float bias = sb1[c];
#pragma unroll
    for (int i = 0; i < 4; ++i) {
      const int rl = wr + (i << 4) + lr4;
#pragma unroll
      for (int q = 0; q < 4; ++q)
        hidden[((size_t)(row0 + rl + q) << 8) + c] = fmaxf(acc[i][j][q] + bias, 0.f);
    }
  }
}

// ---------------- Logits layer-2 + argmax + histogram + fused scan (last block) ----------------
__global__ __launch_bounds__(256) void logits_kernel(
    const float* __restrict__ hidden, const float* __restrict__ sw2,
    const float* __restrict__ sb2, int* __restrict__ routes, int* meta) {
  __shared__ float logl[32][8];
  const int tid = threadIdx.x;
  const int tok0 = blockIdx.x << 5;
  const int tl = tid >> 3, e2 = tid & 7;
  const float* hp = hidden + ((size_t)(tok0 + tl) << 8);
  float a0 = 0.f, a1 = 0.f, a2 = 0.f, a3 = 0.f;
  for (int q = 0; q < SD; q += 8) {
    const float4 h0 = *(const float4*)&hp[q];
    const float4 h1 = *(const float4*)&hp[q + 4];
    a0 = fmaf(h0.x, sw2[((q + 0) << 3) + e2], a0);
    a1 = fmaf(h0.y, sw2[((q + 1) << 3) + e2], a1);
    a2 = fmaf(h0.z, sw2[((q + 2) << 3) + e2], a2);
    a3 = fmaf(h0.w, sw2[((q + 3) << 3) + e2], a3);
    a0 = fmaf(h1.x, sw2[((q + 4) << 3) + e2], a0);
    a1 = fmaf(h1.y, sw2[((q + 5) << 3) + e2], a1);
    a2 = fmaf(h1.z, sw2[((q + 6) << 3) + e2], a2);
    a3 = fmaf(h1.w, sw2[((q + 7) << 3) + e2], a3);
  }
  logl[tl][e2] = (a0 + a1) + (a2 + a3) + sb2[e2];
  __syncthreads();
  if (tid < 32) {
    float best = logl[tid][0]; int be = 0;
#pragma unroll
    for (int e = 1; e < 8; ++e) {
      const float v = logl[tid][e];
      if (v > best) { best = v; be = e; }
    }
    routes[tok0 + tid] = be;
    atomicAdd(&meta[be], 1);
  }
  // last-block-done: fused scan (replaces scan_kernel launch)
  __syncthreads();
  if (tid == 0) {
    __threadfence();
    const int done = atomicAdd(&meta[26], 1);
    if (done == (int)gridDim.x - 1) {
      int cnt[NE];
#pragma unroll
      for (int e = 0; e < NE; ++e) cnt[e] = atomicAdd(&meta[e], 0);
      int off = 0;
      for (int e = 0; e < NE; ++e) { meta[16 + e] = off; off += cnt[e]; }
      meta[24] = off;
      int nt = 0;
      for (int e = 0; e < NE; ++e) {
        const int s = meta[16 + e], en = meta[16 + e + 1];
        for (int r0 = s; r0 < en; r0 += 128) {
          meta[32 + nt] = e; meta[192 + nt] = r0; meta[352 + nt] = en; ++nt;
        }
      }
      meta[25] = nt;
      __threadfence();
    }
  }
}

// ---------------- Build permutation (token -> grouped position) ----------------
__global__ void perm_kernel(const int* __restrict__ routes, int* meta, int* __restrict__ perm) {
  const int b = blockIdx.x * 256 + threadIdx.x;
  const int r = routes[b];
  const int pos = meta[16 + r] + atomicAdd(&meta[8 + r], 1);
  perm[pos] = b;
}

// ---------------- Gather x rows into grouped order, f32 -> bf16 ----------------
__global__ __launch_bounds__(256) void gatherx_kernel(
    const float* __restrict__ x, const int* __restrict__ perm, u16* __restrict__ xg) {
  const int t = blockIdx.x * 256 + threadIdx.x;
  const int p = t >> 7;
  const int j = (t & 127) << 3;
  const int tok = perm[p];
  const float* s = &x[((size_t)tok << 10) + j];
  const float4 a = *(const float4*)s;
  const float4 b = *(const float4*)(s + 4);
  u16x8 o;
  o[0] = f2bf(a.x); o[1] = f2bf(a.y); o[2] = f2bf(a.z); o[3] = f2bf(a.w);
  o[4] = f2bf(b.x); o[5] = f2bf(b.y); o[6] = f2bf(b.z); o[7] = f2bf(b.w);
  *(u16x8*)&xg[((size_t)p << 10) + j] = o;
}

// ---------------- GEMM1: hid[p][0:2048] = relu(xg[p] @ [ew1[e] | uw1] + eb1[e]/ub1) ----------------
__global__ __launch_bounds__(256) void gemm1_kernel(
    const u16* __restrict__ xg, const u16* __restrict__ ew1t,
    const u16* __restrict__ uw1t, const float* __restrict__ eb1,
    const float* __restrict__ ub1, const int* __restrict__ meta,
    u16* __restrict__ hid) {
  const int nt = meta[25];
  // XCD-chunked, mt-major: grid 2160 = 16 jt x 135 mt
  const int pb = blockIdx.x;
  const int L = (pb & 7) * 270 + (pb >> 3);
  const int mt = L >> 4;
  const int jt = L & 15;
  if (mt >= nt) return;
  const int e = meta[32 + mt], row0 = meta[192 + mt], gend = meta[352 + mt];
  const u16* wbase = (jt < 8)
      ? ew1t + ((size_t)e << 20) + ((size_t)(jt << 7) << 10)
      : uw1t + ((size_t)((jt - 8) << 7) << 10);

  __shared__ u16 sA[2][128 * 32];
  __shared__ u16 sB[2][128 * 32];

  const int tid = threadIdx.x;
  const int lane = tid & 63;
  const int wave = tid >> 6;
  const int wr = (wave >> 1) << 6;
  const int wc = (wave & 1) << 6;

  const int smrow = tid >> 2;
  const int skoff = (((tid & 3) ^ ((tid >> 3) & 3)) << 3);
  const u16* ap0 = xg + (((size_t)(row0 + smrow)) << 10) + skoff;
  const u16* ap1 = xg + (((size_t)(row0 + smrow + 64)) << 10) + skoff;
  const u16* bp0 = wbase + (((size_t)smrow) << 10) + skoff;
  const u16* bp1 = wbase + (((size_t)(smrow + 64)) << 10) + skoff;
  const int ldsoff = wave << 10;

  f32x4 acc[4][4];
#pragma unroll
  for (int i = 0; i < 4; ++i)
#pragma unroll
    for (int j = 0; j < 4; ++j) acc[i][j] = (f32x4){0.f, 0.f, 0.f, 0.f};

  gload16(ap0, (char*)sA[0] + ldsoff);
  gload16(ap1, (char*)sA[0] + 4096 + ldsoff);
  gload16(bp0, (char*)sB[0] + ldsoff);
  gload16(bp1, (char*)sB[0] + 4096 + ldsoff);

  const int sl = (((lane >> 4) ^ ((lane >> 1) & 3)) << 3);
  const int afrag = (wr + (lane & 15)) * 32 + sl;
  const int bfrag = (wc + (lane & 15)) * 32 + sl;

#pragma unroll
  for (int ks = 0; ks < 32; ++ks) {
    const int buf = ks & 1;
    __syncthreads();
    if (ks + 1 < 32) {
      const int k1 = (ks + 1) << 5;
      gload16(ap0 + k1, (char*)sA[buf ^ 1] + ldsoff);
      gload16(ap1 + k1, (char*)sA[buf ^ 1] + 4096 + ldsoff);
      gload16(bp0 + k1, (char*)sB[buf ^ 1] + ldsoff);
      gload16(bp1 + k1, (char*)sB[buf ^ 1] + 4096 + ldsoff);
    }
    bf16x8 av[4], bv[4];
#pragma unroll
    for (int f = 0; f < 4; ++f) {
      av[f] = *(const bf16x8*)&sA[buf][afrag + f * 512];
      bv[f] = *(const bf16x8*)&sB[buf][bfrag + f * 512];
    }
#pragma unroll
    for (int i = 0; i < 4; ++i)
#pragma unroll
      for (int j = 0; j < 4; ++j)
        acc[i][j] = __builtin_amdgcn_mfma_f32_16x16x32_bf16(av[i], bv[j], acc[i][j], 0, 0, 0);
  }

  const int lc = lane & 15;
  const int lr4 = (lane >> 4) << 2;
#pragma unroll
  for (int j = 0; j < 4; ++j) {
    const int c = (jt << 7) + wc + (j << 4) + lc;
    const float bias = (c < 1024) ? eb1[(e << 10) + c] : ub1[c - 1024];
#pragma unroll
    for (int i = 0; i < 4; ++i) {
      const int rl = wr + (i << 4) + lr4;
#pragma unroll
      for (int q = 0; q < 4; ++q) {
        const int p = row0 + rl + q;
        if (p < gend) hid[((size_t)p << 11) + c] = f2bf(fmaxf(acc[i][j][q] + bias, 0.f));
      }
    }
  }
}

// ---------------- GEMM2: out[perm[p]][c] = hid[p] @ [ew2[e]; uw2] + eb2[e] + ub2 ----------------
__global__ __launch_bounds__(256) void gemm2_kernel(
    const u16* __restrict__ hid, const u16* __restrict__ ew2t,
    const u16* __restrict__ uw2t, const float* __restrict__ eb2,
    const float* __restrict__ ub2, const int* __restrict__ meta,
    const int* __restrict__ perm, float* __restrict__ out) {
  const int nt = meta[25];
  // XCD-chunked, mt-major: grid 1080 = 8 jt x 135 mt
  const int pb = blockIdx.x;
  const int L = (pb & 7) * 135 + (pb >> 3);
  const int mt = L >> 3;
  const int jt = L & 7;
  if (mt >= nt) return;
  const int e = meta[32 + mt], row0 = meta[192 + mt], gend = meta[352 + mt];
  const int n0 = jt << 7;

  __shared__ u16 sA[2][128 * 32];
  __shared__ u16 sB[2][128 * 32];

  const int tid = threadIdx.x;
  const int lane = tid & 63;
  const int wave = tid >> 6;
  const int wr = (wave >> 1) << 6;
  const int wc = (wave & 1) << 6;

  const int smrow = tid >> 2;
  const int skoff = (((tid & 3) ^ ((tid >> 3) & 3)) << 3);
  const u16* ap0 = hid + (((size_t)(row0 + smrow)) << 11) + skoff;
  const u16* ap1 = hid + (((size_t)(row0 + smrow + 64)) << 11) + skoff;
  const u16* ebase = ew2t + ((size_t)e << 20);
  const size_t brow0 = (((size_t)(n0 + smrow)) << 10) + skoff;
  const size_t brow1 = (((size_t)(n0 + smrow + 64)) << 10) + skoff;
  const int ldsoff = wave << 10;

  f32x4 acc[4][4];
#pragma unroll
  for (int i = 0; i < 4; ++i)
#pragma unroll
    for (int j = 0; j < 4; ++j) acc[i][j] = (f32x4){0.f, 0.f, 0.f, 0.f};

  gload16(ap0, (char*)sA[0] + ldsoff);
  gload16(ap1, (char*)sA[0] + 4096 + ldsoff);
  gload16(ebase + brow0, (char*)sB[0] + ldsoff);
  gload16(ebase + brow1, (char*)sB[0] + 4096 + ldsoff);

  const int sl = (((lane >> 4) ^ ((lane >> 1) & 3)) << 3);
  const int afrag = (wr + (lane & 15)) * 32 + sl;
  const int bfrag = (wc + (lane & 15)) * 32 + sl;

#pragma unroll
  for (int ks = 0; ks < 64; ++ks) {
    const int buf = ks & 1;
    __syncthreads();
    if (ks + 1 < 64) {
      const int k1 = (ks + 1) << 5;
      const u16* bb = (k1 < 1024) ? ebase : uw2t;
      const int kk = k1 & 1023;
      gload16(ap0 + k1, (char*)sA[buf ^ 1] + ldsoff);
      gload16(ap1 + k1, (char*)sA[buf ^ 1] + 4096 + ldsoff);
      gload16(bb + brow0 + kk, (char*)sB[buf ^ 1] + ldsoff);
      gload16(bb + brow1 + kk, (char*)sB[buf ^ 1] + 4096 + ldsoff);
    }
    bf16x8 av[4], bv[4];
#pragma unroll
    for (int f = 0; f < 4; ++f) {
      av[f] = *(const bf16x8*)&sA[buf][afrag + f * 512];
      bv[f] = *(const bf16x8*)&sB[buf][bfrag + f * 512];
    }
#pragma unroll
    for (int i = 0; i < 4; ++i)
#pragma unroll
      for (int j = 0; j < 4; ++j)
        acc[i][j] = __builtin_amdgcn_mfma_f32_16x16x32_bf16(av[i], bv[j], acc[i][j], 0, 0, 0);
  }

  const int lc = lane & 15;
  const int lr4 = (lane >> 4) << 2;
#pragma unroll
  for (int j = 0; j < 4; ++j) {
    const int c = n0 + wc + (j << 4) + lc;
    const float bias = eb2[(e << 10) + c] + ub2[c];
#pragma unroll
    for (int i = 0; i < 4; ++i) {
      const int rl = wr + (i << 4) + lr4;
#pragma unroll
      for (int q = 0; q < 4; ++q) {
        const int p = row0 + rl + q;
        if (p < gend) out[((size_t)perm[p] << 10) + c] = acc[i][j][q] + bias;
      }
    }
  }
}

extern "C" void kernel_launch(void* const* d_in, const int* in_sizes, int n_in,
                              void* d_out, int out_size, void* d_ws, size_t ws_size,
                              hipStream_t stream) {
  const float* x   = (const float*)d_in[0];
  const float* ue  = (const float*)d_in[1];
  const float* sw1 = (const float*)d_in[2];
  const float* sb1 = (const float*)d_in[3];
  const float* sw2 = (const float*)d_in[4];
  const float* sb2 = (const float*)d_in[5];
  const float* ew1 = (const float*)d_in[6];
  const float* eb1 = (const float*)d_in[7];
  const float* ew2 = (const float*)d_in[8];
  const float* eb2 = (const float*)d_in[9];
  const float* uw1 = (const float*)d_in[10];
  const float* ub1 = (const float*)d_in[11];
  const float* uw2 = (const float*)d_in[12];
  const float* ub2 = (const float*)d_in[13];
  float* out = (float*)d_out;

  char* w = (char*)d_ws;
  int* meta = (int*)w;    w += 4096;
  int* routes = (int*)w;  w += NTOK * 4;
  int* perm = (int*)w;    w += NTOK * 4;
  char* region = w;
  u16* xg   = (u16*)region;                                             // 33,816,576 B
  u16* ew1t = (u16*)(region + 33816576ull);                             // 16 MiB
  u16* ew2t = (u16*)(region + 33816576ull + 16777216ull);               // 16 MiB
  u16* uw1t = (u16*)(region + 33816576ull + 2 * 16777216ull);           // 2 MiB
  u16* uw2t = (u16*)(region + 33816576ull + 2 * 16777216ull + 2097152ull);
  u16* hid  = (u16*)(region + 33816576ull + 2 * 16777216ull + 2 * 2097152ull);  // 67,633,152 B
  const size_t region_sz = 33816576ull + 2 * 16777216ull + 2 * 2097152ull + 67633152ull;
  // router-phase aliases live in the (dead-until-gemm1) hid region / xg region:
  _Float16* aP     = (_Float16*)(region + 33816576ull + 2 * 16777216ull + 2 * 2097152ull);
  float* hidden32  = (float*)region;
  _Float16* bP     = (_Float16*)(region + 16777216ull);
  if (135168ull + region_sz > ws_size) return;

  hipMemsetAsync(meta, 0, 4096, stream);
  prep_kernel<<<12864, 256, 0, stream>>>(ue, aP, sw1, bP, ew1, ew2, uw1, uw2,
                                         ew1t, ew2t, uw1t, uw2t);
  rgemm_kernel<<<512, 256, 0, stream>>>(aP, bP, sb1, hidden32);
  logits_kernel<<<NTOK / 32, 256, 0, stream>>>(hidden32, sw2, sb2, routes, meta);
  perm_kernel<<<NTOK / 256, 256, 0, stream>>>(routes, meta, perm);
  gatherx_kernel<<<(NTOK * 128) / 256, 256, 0, stream>>>(x, perm, xg);
  gemm1_kernel<<<2160, 256, 0, stream>>>(xg, ew1t, uw1t, eb1, ub1, meta, hid);
  gemm2_kernel<<<1080, 256, 0, stream>>>(hid, ew2t, uw2t, eb2, ub2, meta, perm, out);
}